// Round 2
// baseline (1382.408 us; speedup 1.0000x reference)
//
#include <hip/hip_runtime.h>
#include <hip/hip_bf16.h>

// Problem dims
#define NNODE 32
#define NB    64
#define NDIM  32
#define NSTEP 8
#define NE    992
#define NH    64
#define NCAT  96
#define NTT   16

typedef __bf16 bf16;
typedef __attribute__((ext_vector_type(8))) __bf16 bf16x8;
typedef __attribute__((ext_vector_type(4))) float  f32x4;

__device__ __forceinline__ f32x4 mfma_bf16(bf16x8 a, bf16x8 b, f32x4 c) {
  return __builtin_amdgcn_mfma_f32_16x16x32_bf16(a, b, c, 0, 0, 0);
}
__device__ __forceinline__ float sigm(float x) { return 1.0f / (1.0f + __expf(-x)); }
__device__ __forceinline__ float tanh_f(float x) {
  x = fminf(fmaxf(x, -15.0f), 15.0f);
  float e = __expf(2.0f * x);
  return (e - 1.0f) / (e + 1.0f);
}

// Swizzle [3][64][64] float weights into MFMA B-fragment bf16 order.
// Lane L of frag holds B[k=(L>>4)*8+j][n=L&15] for K-chunk kf, N-tile nt.
__global__ void prep_weights(const float* __restrict__ W1, const float* __restrict__ W2,
                             const float* __restrict__ Wi, const float* __restrict__ Wh,
                             bf16* __restrict__ B1, bf16* __restrict__ B2,
                             bf16* __restrict__ GI, bf16* __restrict__ GH) {
  int u = blockIdx.x * 256 + threadIdx.x;
  if (u >= 12288) return;
  int k = u >> 12, i = (u >> 6) & 63, h = u & 63;
  int kf = i >> 5, quad = (i >> 3) & 3, j = i & 7;
  {
    int nn = k * 64 + h;                 // flat N (192) for W1/GI/GH
    int nt = nn >> 4;
    int lane = quad * 16 + (nn & 15);
    int slot = ((nt * 2 + kf) * 64 + lane) * 8 + j;
    B1[slot] = (bf16)W1[u];
    GI[slot] = (bf16)Wi[u];
    GH[slot] = (bf16)Wh[u];
  }
  {
    int ntl = h >> 4;                    // per-type N=64 for W2
    int lane = quad * 16 + (h & 15);
    int slot = k * 4096 + ((ntl * 2 + kf) * 64 + lane) * 8 + j;
    B2[slot] = (bf16)W2[u];
  }
}

// Load ground-truth step t into x_cur (fp32 + bf16 mirrors). Layout [n][b][d].
__global__ void copy_x(const float* __restrict__ x, float* __restrict__ xf,
                       bf16* __restrict__ xb, int t) {
  int u = blockIdx.x * 256 + threadIdx.x;  // 65536
  int n = u >> 11, b = (u >> 5) & 63, d = u & 31;
  float v = x[((b * 32 + n) * 32 + d) * 8 + t];
  xf[u] = v;
  xb[u] = (bf16)v;
}

// Per-block: one edge e, all 64 batches. Two-layer 3-type MLP mixture via MFMA.
__global__ __launch_bounds__(256) void edge_mlp(
    const bf16* __restrict__ xb, const int* __restrict__ es,
    const float* __restrict__ z,
    const bf16* __restrict__ B1, const bf16* __restrict__ B2,
    const float* __restrict__ mb1, const float* __restrict__ mb2,
    float* __restrict__ outm) {
  __shared__ __align__(16) bf16 A[64][72];    // rows=b, cols: [x[row_e] | x[col_e]]
  __shared__ __align__(16) bf16 A2[64][200];  // h1, cols n = k*64+h (192)
  int e = blockIdx.x;
  int tid = threadIdx.x;
  int ccol = es[e];        // es[0][e]
  int crow = es[NE + e];   // es[1][e]; msg = [x[row], x[col]]
  const bf16* s0 = xb + crow * (NB * NDIM);
  const bf16* s1 = xb + ccol * (NB * NDIM);
  for (int u = tid; u < 4096; u += 256) {
    int b = u >> 6, i = u & 63;
    A[b][i] = (i < 32) ? s0[b * 32 + i] : s1[b * 32 + (i & 31)];
  }
  __syncthreads();
  int wv = tid >> 6, ln = tid & 63;
  int quad = ln >> 4, l16 = ln & 15;
  bf16x8 af0 = *(const bf16x8*)&A[wv * 16 + l16][quad * 8];
  bf16x8 af1 = *(const bf16x8*)&A[wv * 16 + l16][32 + quad * 8];
  f32x4 acc[12];
#pragma unroll
  for (int q = 0; q < 12; q++) { f32x4 zz = {0.f, 0.f, 0.f, 0.f}; acc[q] = zz; }
#pragma unroll
  for (int nt = 0; nt < 12; nt++) {
    bf16x8 w0 = *(const bf16x8*)&B1[(nt * 2 + 0) * 512 + ln * 8];
    bf16x8 w1 = *(const bf16x8*)&B1[(nt * 2 + 1) * 512 + ln * 8];
    acc[nt] = mfma_bf16(af0, w0, acc[nt]);
    acc[nt] = mfma_bf16(af1, w1, acc[nt]);
  }
  // h1 = relu(acc + b1), store as bf16 A-operand for layer 2 (C-layout -> LDS)
#pragma unroll
  for (int nt = 0; nt < 12; nt++) {
    int n = nt * 16 + l16;
    float bias = mb1[n];
#pragma unroll
    for (int r = 0; r < 4; r++) {
      float v = acc[nt][r] + bias;
      A2[wv * 16 + quad * 4 + r][n] = (bf16)(v > 0.f ? v : 0.f);
    }
  }
  __syncthreads();
  bf16x8 a2[3][2];
#pragma unroll
  for (int kt = 0; kt < 3; kt++)
#pragma unroll
    for (int kf = 0; kf < 2; kf++)
      a2[kt][kf] = *(const bf16x8*)&A2[wv * 16 + l16][kt * 64 + kf * 32 + quad * 8];
  f32x4 acc2[12];
#pragma unroll
  for (int q = 0; q < 12; q++) { f32x4 zz = {0.f, 0.f, 0.f, 0.f}; acc2[q] = zz; }
#pragma unroll
  for (int kt = 0; kt < 3; kt++)
#pragma unroll
    for (int nt = 0; nt < 4; nt++) {
      bf16x8 w0 = *(const bf16x8*)&B2[kt * 4096 + (nt * 2 + 0) * 512 + ln * 8];
      bf16x8 w1 = *(const bf16x8*)&B2[kt * 4096 + (nt * 2 + 1) * 512 + ln * 8];
      acc2[kt * 4 + nt] = mfma_bf16(a2[kt][0], w0, acc2[kt * 4 + nt]);
      acc2[kt * 4 + nt] = mfma_bf16(a2[kt][1], w1, acc2[kt * 4 + nt]);
    }
  // mix with z, /K
#pragma unroll
  for (int r = 0; r < 4; r++) {
    int b = wv * 16 + quad * 4 + r;
    const float* zp = z + (b * NE + e) * 3;
    float z0 = zp[0], z1 = zp[1], z2 = zp[2];
#pragma unroll
    for (int nt = 0; nt < 4; nt++) {
      int o = nt * 16 + l16;
      float h0 = acc2[nt][r]     + mb2[o];       h0 = h0 > 0.f ? h0 : 0.f;
      float h1 = acc2[4 + nt][r] + mb2[64 + o];  h1 = h1 > 0.f ? h1 : 0.f;
      float h2 = acc2[8 + nt][r] + mb2[128 + o]; h2 = h2 > 0.f ? h2 : 0.f;
      outm[(e * 64 + b) * 64 + o] = (h0 * z0 + h1 * z1 + h2 * z2) * (1.0f / 3.0f);
    }
  }
}

// GRU over edge state: h_edge = GRU(msgs_raw, h_edge), in place. One block per edge.
__global__ __launch_bounds__(256) void edge_gru(
    const float* __restrict__ inp, float* __restrict__ hed,
    const bf16* __restrict__ GI, const bf16* __restrict__ GH,
    const float* __restrict__ gbi, const float* __restrict__ gbh) {
  __shared__ __align__(16) bf16 Ai[64][72];
  __shared__ __align__(16) bf16 Ah[64][72];
  int e = blockIdx.x;
  int tid = threadIdx.x;
  const float* pi = inp + e * 4096;
  const float* ph = hed + e * 4096;
  for (int u = tid; u < 4096; u += 256) {
    Ai[u >> 6][u & 63] = (bf16)pi[u];
    Ah[u >> 6][u & 63] = (bf16)ph[u];
  }
  __syncthreads();
  int wv = tid >> 6, ln = tid & 63;
  int quad = ln >> 4, l16 = ln & 15;
  bf16x8 ai0 = *(const bf16x8*)&Ai[wv * 16 + l16][quad * 8];
  bf16x8 ai1 = *(const bf16x8*)&Ai[wv * 16 + l16][32 + quad * 8];
  bf16x8 ah0 = *(const bf16x8*)&Ah[wv * 16 + l16][quad * 8];
  bf16x8 ah1 = *(const bf16x8*)&Ah[wv * 16 + l16][32 + quad * 8];
  f32x4 gi[12], gh[12];
#pragma unroll
  for (int q = 0; q < 12; q++) { f32x4 zz = {0.f, 0.f, 0.f, 0.f}; gi[q] = zz; gh[q] = zz; }
#pragma unroll
  for (int nt = 0; nt < 12; nt++) {
    bf16x8 wi0 = *(const bf16x8*)&GI[(nt * 2 + 0) * 512 + ln * 8];
    bf16x8 wi1 = *(const bf16x8*)&GI[(nt * 2 + 1) * 512 + ln * 8];
    bf16x8 wh0 = *(const bf16x8*)&GH[(nt * 2 + 0) * 512 + ln * 8];
    bf16x8 wh1 = *(const bf16x8*)&GH[(nt * 2 + 1) * 512 + ln * 8];
    gi[nt] = mfma_bf16(ai0, wi0, gi[nt]);
    gi[nt] = mfma_bf16(ai1, wi1, gi[nt]);
    gh[nt] = mfma_bf16(ah0, wh0, gh[nt]);
    gh[nt] = mfma_bf16(ah1, wh1, gh[nt]);
  }
#pragma unroll
  for (int r = 0; r < 4; r++) {
    int b = wv * 16 + quad * 4 + r;
#pragma unroll
    for (int nt = 0; nt < 4; nt++) {
      int o = nt * 16 + l16;
      float xr = gi[nt][r]     + gbi[o]       + gh[nt][r]     + gbh[o];
      float xi = gi[4 + nt][r] + gbi[64 + o]  + gh[4 + nt][r] + gbh[64 + o];
      float xn = gi[8 + nt][r] + gbi[128 + o];
      float hn = gh[8 + nt][r] + gbh[128 + o];
      float rg = sigm(xr);
      float ig = sigm(xi);
      float ng = tanh_f(xn + rg * hn);
      float hv = ph[b * 64 + o];  // old state (this lane owns this slot)
      hed[e * 4096 + b * 64 + o] = (1.0f - ig) * ng + ig * hv;
    }
  }
}

// scatter-mean: col = e/31 blocks are contiguous (permutations order); counts == 31.
__global__ void agg_sum(const float* __restrict__ hed, float* __restrict__ aggb) {
  int u = blockIdx.x * 256 + threadIdx.x;  // 131072 = 32*64*64, layout [n][b][o]
  int n = u >> 12;
  int bo = u & 4095;
  const float* p = hed + n * 31 * 4096 + bo;
  float s = 0.f;
#pragma unroll
  for (int j = 0; j < 31; j++) s += p[j * 4096];
  aggb[u] = s * (1.0f / 31.0f);
}

// Node side: GRU(96) + 3-layer MLP head, wave-per-(n,b)-row. Writes x_cur and outputs.
__global__ __launch_bounds__(256) void node_step(
    const float* __restrict__ aggb, float* __restrict__ xf, bf16* __restrict__ xb,
    float* __restrict__ hnode,
    const float* __restrict__ gnWi, const float* __restrict__ gnbi,
    const float* __restrict__ gnWh, const float* __restrict__ gnbh,
    const float* __restrict__ oW1, const float* __restrict__ ob1,
    const float* __restrict__ oW2, const float* __restrict__ ob2,
    const float* __restrict__ oW3, const float* __restrict__ ob3,
    float* __restrict__ out, int t, int use_gru) {
  __shared__ float c0[4][NCAT];
  __shared__ float cn[4][NCAT];
  __shared__ float hv[4][NCAT];
  __shared__ float s1[4][64];
  __shared__ float s2[4][64];
  int tid = threadIdx.x, wv = tid >> 6, ln = tid & 63;
  int row = blockIdx.x * 4 + wv;  // 0..2047, row = n*64 + b
  int n = row >> 6, b = row & 63;
  float xin = 0.0f;
  if (ln < 32) {
    xin = xf[n * 2048 + b * 32 + ln];
    c0[wv][ln] = xin;
    c0[wv][64 + ln] = aggb[row * 64 + 32 + ln];
  } else {
    c0[wv][ln] = aggb[row * 64 + (ln - 32)];
  }
  if (use_gru) {
    hv[wv][ln] = hnode[row * 96 + ln];
    if (ln < 32) hv[wv][64 + ln] = hnode[row * 96 + 64 + ln];
  }
  __syncthreads();
  if (use_gru) {
    for (int c = ln; c < 96; c += 64) {
      float si0 = gnbi[c],       sh0 = gnbh[c];
      float si1 = gnbi[96 + c],  sh1 = gnbh[96 + c];
      float si2 = gnbi[192 + c], sh2 = gnbh[192 + c];
      for (int i = 0; i < 96; i++) {
        float cv = c0[wv][i], hh = hv[wv][i];
        si0 += cv * gnWi[i * 96 + c];
        sh0 += hh * gnWh[i * 96 + c];
        si1 += cv * gnWi[(96 + i) * 96 + c];
        sh1 += hh * gnWh[(96 + i) * 96 + c];
        si2 += cv * gnWi[(192 + i) * 96 + c];
        sh2 += hh * gnWh[(192 + i) * 96 + c];
      }
      float rg = sigm(si0 + sh0);
      float ig = sigm(si1 + sh1);
      float ng = tanh_f(si2 + rg * sh2);
      float v = (1.0f - ig) * ng + ig * hv[wv][c];
      cn[wv][c] = v;
      hnode[row * 96 + c] = v;
    }
  } else {
    for (int c = ln; c < 96; c += 64) {
      float v = c0[wv][c];
      cn[wv][c] = v;
      hnode[row * 96 + c] = v;
    }
  }
  __syncthreads();
  {
    float a = ob1[ln];
    for (int i = 0; i < 96; i++) a += cn[wv][i] * oW1[i * 64 + ln];
    s1[wv][ln] = a > 0.f ? a : 0.f;
  }
  __syncthreads();
  {
    float a = ob2[ln];
    for (int i = 0; i < 64; i++) a += s1[wv][i] * oW2[i * 64 + ln];
    s2[wv][ln] = a > 0.f ? a : 0.f;
  }
  __syncthreads();
  if (ln < 32) {
    float a = ob3[ln];
    for (int i = 0; i < 64; i++) a += s2[wv][i] * oW3[i * 32 + ln];
    float xm = xin + a;
    xf[n * 2048 + b * 32 + ln] = xm;
    xb[n * 2048 + b * 32 + ln] = (bf16)xm;
    int base = (b * 32 + n) * 32 + ln;
    out[524288 + base * 16 + t]  = xm;   // x_hat (copy 1)
    out[1572864 + base * 16 + t] = xm;   // x_hat (copy 2)
    if (t >= 8) out[base * 8 + (t - 8)] = xm;  // prediction window
  }
}

extern "C" void kernel_launch(void* const* d_in, const int* in_sizes, int n_in,
                              void* d_out, int out_size, void* d_ws, size_t ws_size,
                              hipStream_t stream) {
  const float* x     = (const float*)d_in[0];
  const float* z     = (const float*)d_in[1];
  const int*   es    = (const int*)d_in[2];
  const float* msgW1 = (const float*)d_in[6];
  const float* msgb1 = (const float*)d_in[7];
  const float* msgW2 = (const float*)d_in[8];
  const float* msgb2 = (const float*)d_in[9];
  const float* oW1   = (const float*)d_in[10];
  const float* ob1   = (const float*)d_in[11];
  const float* oW2   = (const float*)d_in[12];
  const float* ob2   = (const float*)d_in[13];
  const float* oW3   = (const float*)d_in[14];
  const float* ob3   = (const float*)d_in[15];
  const float* geWi  = (const float*)d_in[16];
  const float* gebi  = (const float*)d_in[17];
  const float* geWh  = (const float*)d_in[18];
  const float* gebh  = (const float*)d_in[19];
  const float* gnWi  = (const float*)d_in[20];
  const float* gnbi  = (const float*)d_in[21];
  const float* gnWh  = (const float*)d_in[22];
  const float* gnbh  = (const float*)d_in[23];
  float* out = (float*)d_out;

  char* p = (char*)d_ws;
  float* xf    = (float*)p;  p += 65536 * 4;
  bf16*  xb    = (bf16*)p;   p += 65536 * 2;
  float* hed   = (float*)p;  p += (size_t)NE * 64 * 64 * 4;  // 16.25 MB
  float* msgs  = (float*)p;  p += (size_t)NE * 64 * 64 * 4;
  float* aggb  = (float*)p;  p += 131072 * 4;
  float* hnode = (float*)p;  p += 196608 * 4;
  bf16*  B1sw  = (bf16*)p;   p += 12288 * 2;
  bf16*  B2sw  = (bf16*)p;   p += 12288 * 2;
  bf16*  GIsw  = (bf16*)p;   p += 12288 * 2;
  bf16*  GHsw  = (bf16*)p;   p += 12288 * 2;

  prep_weights<<<48, 256, 0, stream>>>(msgW1, msgW2, geWi, geWh, B1sw, B2sw, GIsw, GHsw);

  for (int t = 0; t < NTT; t++) {
    if (t < NSTEP) copy_x<<<256, 256, 0, stream>>>(x, xf, xb, t);
    float* mlp_out = (t == 0) ? hed : msgs;
    edge_mlp<<<NE, 256, 0, stream>>>(xb, es, z, B1sw, B2sw, msgb1, msgb2, mlp_out);
    if (t > 0)
      edge_gru<<<NE, 256, 0, stream>>>(msgs, hed, GIsw, GHsw, gebi, gebh);
    agg_sum<<<512, 256, 0, stream>>>(hed, aggb);
    node_step<<<512, 256, 0, stream>>>(aggb, xf, xb, hnode,
                                       gnWi, gnbi, gnWh, gnbh,
                                       oW1, ob1, oW2, ob2, oW3, ob3,
                                       out, t, t > 0 ? 1 : 0);
  }
}

// Round 3
// 987.751 us; speedup vs baseline: 1.3996x; 1.3996x over previous
//
#include <hip/hip_runtime.h>
#include <hip/hip_bf16.h>

// Problem dims
#define NNODE 32
#define NB    64
#define NDIM  32
#define NSTEP 8
#define NE    992
#define NH    64
#define NCAT  96
#define NTT   16

typedef __bf16 bf16;
typedef __attribute__((ext_vector_type(8))) __bf16 bf16x8;
typedef __attribute__((ext_vector_type(4))) float  f32x4;

__device__ __forceinline__ f32x4 mfma_bf16(bf16x8 a, bf16x8 b, f32x4 c) {
  return __builtin_amdgcn_mfma_f32_16x16x32_bf16(a, b, c, 0, 0, 0);
}
__device__ __forceinline__ float sigm(float x) { return 1.0f / (1.0f + __expf(-x)); }
__device__ __forceinline__ float tanh_f(float x) {
  x = fminf(fmaxf(x, -15.0f), 15.0f);
  float e = __expf(2.0f * x);
  return (e - 1.0f) / (e + 1.0f);
}

// ---------------------------------------------------------------------------
// Swizzle all weights into MFMA B-fragment bf16 order.
// For B[K x N]: frag f = nt*KF + kf holds, at lane L, j=0..7:
//   B[kf*32 + (L>>4)*8 + j][nt*16 + (L&15)]
// ---------------------------------------------------------------------------
__global__ void prep_weights(
    const float* __restrict__ msgW1, const float* __restrict__ msgW2,
    const float* __restrict__ geWi,  const float* __restrict__ geWh,
    const float* __restrict__ gnWi,  const float* __restrict__ gnWh,
    const float* __restrict__ oW1,   const float* __restrict__ oW2,
    const float* __restrict__ oW3,
    bf16* __restrict__ B1, bf16* __restrict__ B2,
    bf16* __restrict__ GI, bf16* __restrict__ GH,
    bf16* __restrict__ GN,
    bf16* __restrict__ OW1s, bf16* __restrict__ OW2s, bf16* __restrict__ OW3s) {
  int u = blockIdx.x * 256 + threadIdx.x;
  if (u < 12288) {
    // msgW1/geWi/geWh [3][64][64] -> flat N=192, K=64 (KF=2, NT=12)
    int k = u >> 12, i = (u >> 6) & 63, h = u & 63;
    int kf = i >> 5, quad = (i >> 3) & 3, j = i & 7;
    int nn = k * 64 + h, nt = nn >> 4, lane = quad * 16 + (nn & 15);
    int slot = ((nt * 2 + kf) * 64 + lane) * 8 + j;
    B1[slot] = (bf16)msgW1[u];
    GI[slot] = (bf16)geWi[u];
    GH[slot] = (bf16)geWh[u];
    // msgW2 block-diagonal per edge type: K=64, N=64 (KF=2, NT=4)
    int ntl = h >> 4, lane2 = quad * 16 + (h & 15);
    int slot2 = k * 4096 + ((ntl * 2 + kf) * 64 + lane2) * 8 + j;
    B2[slot2] = (bf16)msgW2[u];
  } else if (u < 39936) {
    // gnWi/gnWh [3][96][96] -> flat N=288, K=96 (KF=3, NT=18)
    int v = u - 12288;
    int kk = v / 9216, rem = v % 9216, i = rem / 96, h = rem % 96;
    int kf = i >> 5, loc = i & 31, quad = loc >> 3, j = loc & 7;
    int nn = kk * 96 + h, nt = nn >> 4, lane = quad * 16 + (nn & 15);
    int slot = ((nt * 3 + kf) * 64 + lane) * 8 + j;
    GN[slot]         = (bf16)gnWi[v];
    GN[27648 + slot] = (bf16)gnWh[v];
  } else if (u < 46080) {
    // oW1 [96][64]: K=96 (KF=3), N=64 (NT=4)
    int v = u - 39936; int i = v >> 6, h = v & 63;
    int kf = i >> 5, loc = i & 31, quad = loc >> 3, j = loc & 7;
    int nt = h >> 4, lane = quad * 16 + (h & 15);
    OW1s[((nt * 3 + kf) * 64 + lane) * 8 + j] = (bf16)oW1[v];
  } else if (u < 50176) {
    // oW2 [64][64]: KF=2, NT=4
    int v = u - 46080; int i = v >> 6, h = v & 63;
    int kf = i >> 5, quad = (i >> 3) & 3, j = i & 7;
    int nt = h >> 4, lane = quad * 16 + (h & 15);
    OW2s[((nt * 2 + kf) * 64 + lane) * 8 + j] = (bf16)oW2[v];
  } else if (u < 52224) {
    // oW3 [64][32]: KF=2, NT=2
    int v = u - 50176; int i = v >> 5, h = v & 31;
    int kf = i >> 5, quad = (i >> 3) & 3, j = i & 7;
    int nt = h >> 4, lane = quad * 16 + (h & 15);
    OW3s[((nt * 2 + kf) * 64 + lane) * 8 + j] = (bf16)oW3[v];
  }
}

// ---------------------------------------------------------------------------
// K1: per edge e (992 blocks): msg MLP mixture (MFMA) + edge GRU (MFMA).
// Writes hed[e][b][o] fp32 (at t==0: hed = msgs mix directly).
// ---------------------------------------------------------------------------
__global__ __launch_bounds__(256) void edge_step(
    const float* __restrict__ x, const float* __restrict__ xf,
    const int* __restrict__ es, const float* __restrict__ z,
    const bf16* __restrict__ B1, const bf16* __restrict__ B2,
    const float* __restrict__ mb1, const float* __restrict__ mb2,
    const bf16* __restrict__ GI, const bf16* __restrict__ GH,
    const float* __restrict__ gbi, const float* __restrict__ gbh,
    float* __restrict__ hed, int t) {
  __shared__ __align__(16) bf16 A[64][72];    // [b][cat(x[row],x[col])]
  __shared__ __align__(16) bf16 A2[64][200];  // h1 (192 cols)
  __shared__ __align__(16) bf16 Am[64][72];   // msgs mix (64 cols)
  __shared__ __align__(16) bf16 Ah[64][72];   // h_edge old (64 cols)
  int e = blockIdx.x, tid = threadIdx.x;
  int ccol = es[e];        // aggregation target (block-contiguous: e/31)
  int crow = es[NE + e];
  // stage inputs
  if (t < NSTEP) {
    for (int u = tid; u < 4096; u += 256) {
      int b = u >> 6, i = u & 63;
      int node = (i < 32) ? crow : ccol;
      A[b][i] = (bf16)x[((b * 32 + node) * 32 + (i & 31)) * 8 + t];
    }
  } else {
    for (int u = tid; u < 4096; u += 256) {
      int b = u >> 6, i = u & 63;
      int node = (i < 32) ? crow : ccol;
      A[b][i] = (bf16)xf[node * 2048 + b * 32 + (i & 31)];
    }
  }
  if (t > 0) {
    const float* ph = hed + e * 4096;
    for (int u = tid; u < 4096; u += 256) Ah[u >> 6][u & 63] = (bf16)ph[u];
  }
  __syncthreads();
  int wv = tid >> 6, ln = tid & 63, quad = ln >> 4, l16 = ln & 15;
  bf16x8 af0 = *(const bf16x8*)&A[wv * 16 + l16][quad * 8];
  bf16x8 af1 = *(const bf16x8*)&A[wv * 16 + l16][32 + quad * 8];
  f32x4 acc[12];
#pragma unroll
  for (int q = 0; q < 12; q++) { f32x4 zz = {0.f, 0.f, 0.f, 0.f}; acc[q] = zz; }
#pragma unroll
  for (int nt = 0; nt < 12; nt++) {
    bf16x8 w0 = *(const bf16x8*)&B1[(nt * 2 + 0) * 512 + ln * 8];
    bf16x8 w1 = *(const bf16x8*)&B1[(nt * 2 + 1) * 512 + ln * 8];
    acc[nt] = mfma_bf16(af0, w0, acc[nt]);
    acc[nt] = mfma_bf16(af1, w1, acc[nt]);
  }
#pragma unroll
  for (int nt = 0; nt < 12; nt++) {
    int n = nt * 16 + l16;
    float bias = mb1[n];
#pragma unroll
    for (int r = 0; r < 4; r++) {
      float v = acc[nt][r] + bias;
      A2[wv * 16 + quad * 4 + r][n] = (bf16)(v > 0.f ? v : 0.f);
    }
  }
  __syncthreads();
  bf16x8 a2[3][2];
#pragma unroll
  for (int kt = 0; kt < 3; kt++)
#pragma unroll
    for (int kf = 0; kf < 2; kf++)
      a2[kt][kf] = *(const bf16x8*)&A2[wv * 16 + l16][kt * 64 + kf * 32 + quad * 8];
  f32x4 acc2[12];
#pragma unroll
  for (int q = 0; q < 12; q++) { f32x4 zz = {0.f, 0.f, 0.f, 0.f}; acc2[q] = zz; }
#pragma unroll
  for (int kt = 0; kt < 3; kt++)
#pragma unroll
    for (int nt = 0; nt < 4; nt++) {
      bf16x8 w0 = *(const bf16x8*)&B2[kt * 4096 + (nt * 2 + 0) * 512 + ln * 8];
      bf16x8 w1 = *(const bf16x8*)&B2[kt * 4096 + (nt * 2 + 1) * 512 + ln * 8];
      acc2[kt * 4 + nt] = mfma_bf16(a2[kt][0], w0, acc2[kt * 4 + nt]);
      acc2[kt * 4 + nt] = mfma_bf16(a2[kt][1], w1, acc2[kt * 4 + nt]);
    }
  // mix with z, /K
  float mix[4][4];  // [r][nt]
#pragma unroll
  for (int r = 0; r < 4; r++) {
    int b = wv * 16 + quad * 4 + r;
    const float* zp = z + (b * NE + e) * 3;
    float z0 = zp[0], z1 = zp[1], z2 = zp[2];
#pragma unroll
    for (int nt = 0; nt < 4; nt++) {
      int o = nt * 16 + l16;
      float h0 = acc2[nt][r]     + mb2[o];       h0 = h0 > 0.f ? h0 : 0.f;
      float h1 = acc2[4 + nt][r] + mb2[64 + o];  h1 = h1 > 0.f ? h1 : 0.f;
      float h2 = acc2[8 + nt][r] + mb2[128 + o]; h2 = h2 > 0.f ? h2 : 0.f;
      mix[r][nt] = (h0 * z0 + h1 * z1 + h2 * z2) * (1.0f / 3.0f);
    }
  }
  if (t == 0) {
#pragma unroll
    for (int r = 0; r < 4; r++) {
      int b = wv * 16 + quad * 4 + r;
#pragma unroll
      for (int nt = 0; nt < 4; nt++)
        hed[e * 4096 + b * 64 + nt * 16 + l16] = mix[r][nt];
    }
    return;
  }
  // stage mix for GRU A-operand
#pragma unroll
  for (int r = 0; r < 4; r++)
#pragma unroll
    for (int nt = 0; nt < 4; nt++)
      Am[wv * 16 + quad * 4 + r][nt * 16 + l16] = (bf16)mix[r][nt];
  __syncthreads();
  bf16x8 ai0 = *(const bf16x8*)&Am[wv * 16 + l16][quad * 8];
  bf16x8 ai1 = *(const bf16x8*)&Am[wv * 16 + l16][32 + quad * 8];
  bf16x8 ah0 = *(const bf16x8*)&Ah[wv * 16 + l16][quad * 8];
  bf16x8 ah1 = *(const bf16x8*)&Ah[wv * 16 + l16][32 + quad * 8];
  f32x4 gi[12], gh[12];
#pragma unroll
  for (int q = 0; q < 12; q++) { f32x4 zz = {0.f, 0.f, 0.f, 0.f}; gi[q] = zz; gh[q] = zz; }
#pragma unroll
  for (int nt = 0; nt < 12; nt++) {
    bf16x8 wi0 = *(const bf16x8*)&GI[(nt * 2 + 0) * 512 + ln * 8];
    bf16x8 wi1 = *(const bf16x8*)&GI[(nt * 2 + 1) * 512 + ln * 8];
    bf16x8 wh0 = *(const bf16x8*)&GH[(nt * 2 + 0) * 512 + ln * 8];
    bf16x8 wh1 = *(const bf16x8*)&GH[(nt * 2 + 1) * 512 + ln * 8];
    gi[nt] = mfma_bf16(ai0, wi0, gi[nt]);
    gi[nt] = mfma_bf16(ai1, wi1, gi[nt]);
    gh[nt] = mfma_bf16(ah0, wh0, gh[nt]);
    gh[nt] = mfma_bf16(ah1, wh1, gh[nt]);
  }
#pragma unroll
  for (int r = 0; r < 4; r++) {
    int b = wv * 16 + quad * 4 + r;
#pragma unroll
    for (int nt = 0; nt < 4; nt++) {
      int o = nt * 16 + l16;
      float xr = gi[nt][r]     + gbi[o]       + gh[nt][r]     + gbh[o];
      float xi = gi[4 + nt][r] + gbi[64 + o]  + gh[4 + nt][r] + gbh[64 + o];
      float xn = gi[8 + nt][r] + gbi[128 + o];
      float hn = gh[8 + nt][r] + gbh[128 + o];
      float rg = sigm(xr);
      float ig = sigm(xi);
      float ng = tanh_f(xn + rg * hn);
      float hv = hed[e * 4096 + b * 64 + o];
      hed[e * 4096 + b * 64 + o] = (1.0f - ig) * ng + ig * hv;
    }
  }
}

// ---------------------------------------------------------------------------
// K2: per (node, b-quarter) (128 blocks): scatter-mean agg + node GRU (MFMA)
// + 3-layer out-MLP (MFMA). Writes xf, hnode, and the outputs.
// ---------------------------------------------------------------------------
__global__ __launch_bounds__(256) void node_kernel(
    const float* __restrict__ x, const float* __restrict__ hed,
    float* __restrict__ xf, float* __restrict__ hnode,
    const bf16* __restrict__ GN,
    const float* __restrict__ gnbi, const float* __restrict__ gnbh,
    const bf16* __restrict__ OW1, const float* __restrict__ ob1,
    const bf16* __restrict__ OW2, const float* __restrict__ ob2,
    const bf16* __restrict__ OW3, const float* __restrict__ ob3,
    float* __restrict__ out, int t) {
  __shared__ float aggf[16][64];
  __shared__ float xinf[16][32];
  __shared__ float hvf[16][96];
  __shared__ __align__(16) bf16 c0b[16][112];
  __shared__ __align__(16) bf16 hvb[16][112];
  __shared__ float gsum[2][16][290];
  __shared__ __align__(16) bf16 cnb[16][112];
  __shared__ __align__(16) bf16 s1b[16][112];
  __shared__ __align__(16) bf16 s2b[16][112];
  int nq = blockIdx.x, n = nq >> 2, q = nq & 3;
  int tid = threadIdx.x;
  // --- aggregation: mean over this node's 31 contiguous edges ---
  {
    int r = tid >> 4, o4 = tid & 15;
    const float4* base = (const float4*)hed + (size_t)n * 31 * 1024 + (q * 16 + r) * 16 + o4;
    float4 s = {0.f, 0.f, 0.f, 0.f};
#pragma unroll
    for (int e2 = 0; e2 < 31; e2++) {
      float4 v = base[e2 * 1024];
      s.x += v.x; s.y += v.y; s.z += v.z; s.w += v.w;
    }
    const float inv = 1.0f / 31.0f;
    s.x *= inv; s.y *= inv; s.z *= inv; s.w *= inv;
    int o = o4 * 4;
    aggf[r][o] = s.x; aggf[r][o + 1] = s.y; aggf[r][o + 2] = s.z; aggf[r][o + 3] = s.w;
    c0b[r][32 + o] = (bf16)s.x; c0b[r][33 + o] = (bf16)s.y;
    c0b[r][34 + o] = (bf16)s.z; c0b[r][35 + o] = (bf16)s.w;
  }
  // --- x_in ---
  if (tid < 128) {
    int r = tid >> 3, d0 = (tid & 7) * 4;
    int b = q * 16 + r;
#pragma unroll
    for (int k = 0; k < 4; k++) {
      float v = (t < NSTEP) ? x[((b * 32 + n) * 32 + d0 + k) * 8 + t]
                            : xf[n * 2048 + b * 32 + d0 + k];
      xinf[r][d0 + k] = v;
      c0b[r][d0 + k] = (bf16)v;
    }
  }
  // --- h_node old ---
  if (t > 0) {
    int r = tid >> 4, c0 = (tid & 15) * 6;
    int row = n * 64 + q * 16 + r;
#pragma unroll
    for (int k = 0; k < 6; k++) {
      float v = hnode[row * 96 + c0 + k];
      hvf[r][c0 + k] = v;
      hvb[r][c0 + k] = (bf16)v;
    }
  }
  __syncthreads();
  int wv = tid >> 6, ln = tid & 63, quad = ln >> 4, l16 = ln & 15;
  // --- node GRU gates via MFMA: gi = c0@gnWi, gh = hv@gnWh (N=288 each) ---
  if (t > 0) {
    int mat = wv >> 1, sel = wv & 1;
    const bf16(*Ab)[112] = mat ? hvb : c0b;
    bf16x8 af[3];
#pragma unroll
    for (int kf = 0; kf < 3; kf++)
      af[kf] = *(const bf16x8*)&Ab[l16][kf * 32 + quad * 8];
    const bf16* W = GN + mat * 27648;
    f32x4 acc[9];
#pragma unroll
    for (int q2 = 0; q2 < 9; q2++) { f32x4 zz = {0.f, 0.f, 0.f, 0.f}; acc[q2] = zz; }
#pragma unroll
    for (int nt2 = 0; nt2 < 9; nt2++) {
      int nt = sel * 9 + nt2;
#pragma unroll
      for (int kf = 0; kf < 3; kf++) {
        bf16x8 bfrag = *(const bf16x8*)&W[((nt * 3 + kf) * 64 + ln) * 8];
        acc[nt2] = mfma_bf16(af[kf], bfrag, acc[nt2]);
      }
    }
#pragma unroll
    for (int nt2 = 0; nt2 < 9; nt2++) {
      int col = (sel * 9 + nt2) * 16 + l16;
#pragma unroll
      for (int rr = 0; rr < 4; rr++)
        gsum[mat][quad * 4 + rr][col] = acc[nt2][rr];
    }
  }
  __syncthreads();
  // --- gates elementwise -> cn (new cat / h_node) ---
  {
    int r = tid >> 4, cb = (tid & 15) * 6;
    int row = n * 64 + q * 16 + r;
#pragma unroll
    for (int k = 0; k < 6; k++) {
      int c = cb + k;
      float v;
      if (t > 0) {
        float xr = gsum[0][r][c] + gnbi[c] + gsum[1][r][c] + gnbh[c];
        float xi = gsum[0][r][96 + c] + gnbi[96 + c] + gsum[1][r][96 + c] + gnbh[96 + c];
        float xn = gsum[0][r][192 + c] + gnbi[192 + c];
        float hn = gsum[1][r][192 + c] + gnbh[192 + c];
        float rg = sigm(xr);
        float ig = sigm(xi);
        float ng = tanh_f(xn + rg * hn);
        v = (1.0f - ig) * ng + ig * hvf[r][c];
      } else {
        v = (c < 32) ? xinf[r][c] : aggf[r][c - 32];
      }
      cnb[r][c] = (bf16)v;
      hnode[row * 96 + c] = v;
    }
  }
  __syncthreads();
  // --- h1 = relu(cn @ oW1 + b1): wave wv -> N-tile wv, K=96 ---
  {
    bf16x8 af[3];
#pragma unroll
    for (int kf = 0; kf < 3; kf++)
      af[kf] = *(const bf16x8*)&cnb[l16][kf * 32 + quad * 8];
    f32x4 acc = {0.f, 0.f, 0.f, 0.f};
#pragma unroll
    for (int kf = 0; kf < 3; kf++) {
      bf16x8 bfrag = *(const bf16x8*)&OW1[((wv * 3 + kf) * 64 + ln) * 8];
      acc = mfma_bf16(af[kf], bfrag, acc);
    }
    int col = wv * 16 + l16;
    float bias = ob1[col];
#pragma unroll
    for (int rr = 0; rr < 4; rr++) {
      float vv = acc[rr] + bias;
      s1b[quad * 4 + rr][col] = (bf16)(vv > 0.f ? vv : 0.f);
    }
  }
  __syncthreads();
  // --- h2 = relu(h1 @ oW2 + b2): K=64 ---
  {
    bf16x8 af[2];
#pragma unroll
    for (int kf = 0; kf < 2; kf++)
      af[kf] = *(const bf16x8*)&s1b[l16][kf * 32 + quad * 8];
    f32x4 acc = {0.f, 0.f, 0.f, 0.f};
#pragma unroll
    for (int kf = 0; kf < 2; kf++) {
      bf16x8 bfrag = *(const bf16x8*)&OW2[((wv * 2 + kf) * 64 + ln) * 8];
      acc = mfma_bf16(af[kf], bfrag, acc);
    }
    int col = wv * 16 + l16;
    float bias = ob2[col];
#pragma unroll
    for (int rr = 0; rr < 4; rr++) {
      float vv = acc[rr] + bias;
      s2b[quad * 4 + rr][col] = (bf16)(vv > 0.f ? vv : 0.f);
    }
  }
  __syncthreads();
  // --- delta = h2 @ oW3 + b3; x_m = x_in + delta; write outputs ---
  if (wv < 2) {
    bf16x8 af[2];
#pragma unroll
    for (int kf = 0; kf < 2; kf++)
      af[kf] = *(const bf16x8*)&s2b[l16][kf * 32 + quad * 8];
    f32x4 acc = {0.f, 0.f, 0.f, 0.f};
#pragma unroll
    for (int kf = 0; kf < 2; kf++) {
      bf16x8 bfrag = *(const bf16x8*)&OW3[((wv * 2 + kf) * 64 + ln) * 8];
      acc = mfma_bf16(af[kf], bfrag, acc);
    }
    int d = wv * 16 + l16;
    float bias = ob3[d];
#pragma unroll
    for (int rr = 0; rr < 4; rr++) {
      int r = quad * 4 + rr;
      int b = q * 16 + r;
      float xm = xinf[r][d] + acc[rr] + bias;
      xf[n * 2048 + b * 32 + d] = xm;
      int base = (b * 32 + n) * 32 + d;
      out[524288 + base * 16 + t] = xm;
      out[1572864 + base * 16 + t] = xm;
      if (t >= NSTEP) out[base * 8 + (t - NSTEP)] = xm;
    }
  }
}

extern "C" void kernel_launch(void* const* d_in, const int* in_sizes, int n_in,
                              void* d_out, int out_size, void* d_ws, size_t ws_size,
                              hipStream_t stream) {
  const float* x     = (const float*)d_in[0];
  const float* z     = (const float*)d_in[1];
  const int*   es    = (const int*)d_in[2];
  const float* msgW1 = (const float*)d_in[6];
  const float* msgb1 = (const float*)d_in[7];
  const float* msgW2 = (const float*)d_in[8];
  const float* msgb2 = (const float*)d_in[9];
  const float* oW1   = (const float*)d_in[10];
  const float* ob1   = (const float*)d_in[11];
  const float* oW2   = (const float*)d_in[12];
  const float* ob2   = (const float*)d_in[13];
  const float* oW3   = (const float*)d_in[14];
  const float* ob3   = (const float*)d_in[15];
  const float* geWi  = (const float*)d_in[16];
  const float* gebi  = (const float*)d_in[17];
  const float* geWh  = (const float*)d_in[18];
  const float* gebh  = (const float*)d_in[19];
  const float* gnWi  = (const float*)d_in[20];
  const float* gnbi  = (const float*)d_in[21];
  const float* gnWh  = (const float*)d_in[22];
  const float* gnbh  = (const float*)d_in[23];
  float* out = (float*)d_out;

  char* p = (char*)d_ws;
  float* hed   = (float*)p;  p += (size_t)NE * 64 * 64 * 4;   // 16.25 MB
  float* xf    = (float*)p;  p += 65536 * 4;
  float* hnode = (float*)p;  p += 196608 * 4;
  bf16*  B1sw  = (bf16*)p;   p += 12288 * 2;
  bf16*  B2sw  = (bf16*)p;   p += 12288 * 2;
  bf16*  GIsw  = (bf16*)p;   p += 12288 * 2;
  bf16*  GHsw  = (bf16*)p;   p += 12288 * 2;
  bf16*  GNsw  = (bf16*)p;   p += 55296 * 2;
  bf16*  OW1s  = (bf16*)p;   p += 6144 * 2;
  bf16*  OW2s  = (bf16*)p;   p += 4096 * 2;
  bf16*  OW3s  = (bf16*)p;   p += 2048 * 2;

  prep_weights<<<204, 256, 0, stream>>>(msgW1, msgW2, geWi, geWh, gnWi, gnWh,
                                        oW1, oW2, oW3,
                                        B1sw, B2sw, GIsw, GHsw, GNsw,
                                        OW1s, OW2s, OW3s);

  for (int t = 0; t < NTT; t++) {
    edge_step<<<NE, 256, 0, stream>>>(x, xf, es, z, B1sw, B2sw, msgb1, msgb2,
                                      GIsw, GHsw, gebi, gebh, hed, t);
    node_kernel<<<128, 256, 0, stream>>>(x, hed, xf, hnode, GNsw, gnbi, gnbh,
                                         OW1s, ob1, OW2s, ob2, OW3s, ob3,
                                         out, t);
  }
}